// Round 1
// baseline (125.337 us; speedup 1.0000x reference)
//
#include <hip/hip_runtime.h>
#include <hip/hip_bf16.h>

typedef __attribute__((ext_vector_type(8))) short short8;
typedef __attribute__((ext_vector_type(4))) float floatx4;

#define YP 148
#define XP 160
#define CH_ELEMS (YP*XP)   // 23680 bf16 elems per channel-copy

__device__ __forceinline__ unsigned short f2b(float f){
  unsigned int u = __float_as_uint(f);
  unsigned int r = (u + 0x7fffu + ((u >> 16) & 1u)) >> 16;  // RNE
  return (unsigned short)r;
}

// ---------------- Kernel 1: standardize + build padded wrap copies ----------------
// pad[r][b][c][yy][xx] = xs[(yy-10)%128][(xx-o_r)%128],  o = {10, 11, 16}
__global__ __launch_bounds__(256) void k_std(const float* __restrict__ x,
                                             __hip_bfloat16* __restrict__ pad){
  int bid = blockIdx.x;
  int b = bid >> 5, c = bid & 31;
  int t = threadIdx.x;
  const float* xc = x + ((size_t)(b*32 + c) << 14);
  float s = 0.f, ss = 0.f;
  #pragma unroll 4
  for (int k = 0; k < 64; ++k){
    float v = xc[t + (k << 8)];
    s += v; ss += v*v;
  }
  #pragma unroll
  for (int m = 32; m >= 1; m >>= 1){
    s  += __shfl_xor(s, m);
    ss += __shfl_xor(ss, m);
  }
  __shared__ float rs[4], rss[4], sc[2];
  int wv = t >> 6, ln = t & 63;
  if (ln == 0){ rs[wv] = s; rss[wv] = ss; }
  __syncthreads();
  if (t == 0){
    float S  = rs[0]+rs[1]+rs[2]+rs[3];
    float SS = rss[0]+rss[1]+rss[2]+rss[3];
    float mean = S * (1.f/16384.f);
    float var  = (SS - S*mean) * (1.f/16383.f);   // ddof=1
    float sd = sqrtf(fmaxf(var, 0.f));
    sc[0] = mean;
    sc[1] = (sd < 1e-9f) ? 0.f : 1.f/(sd*128.f);  // 1/(std*sqrt(16384))
  }
  __syncthreads();
  float mean = sc[0], scale = sc[1];
  if (t < 240){
    int r  = (t >= 160) ? 2 : (t >= 80 ? 1 : 0);
    int xd = t - 80*r;
    int o  = (r == 2) ? 16 : (10 + r);
    unsigned int* dst = (unsigned int*)(pad + (size_t)(r*256 + b*32 + c)*CH_ELEMS);
    int sx0 = (2*xd - o + 256) & 127;
    int sx1 = (sx0 + 1) & 127;
    for (int yy = 0; yy < YP; ++yy){
      int sy = (yy + 118) & 127;   // (yy-10) mod 128
      float v0 = (xc[(sy << 7) + sx0] - mean) * scale;
      float v1 = (xc[(sy << 7) + sx1] - mean) * scale;
      unsigned int pk = (unsigned int)f2b(v0) | ((unsigned int)f2b(v1) << 16);
      dst[yy*80 + xd] = pk;
    }
  }
}

// ---------------- Kernel 2: shifted Gram via MFMA ----------------
// grid: bid = (combo*2 + mh)*8 + b ; 512 blocks, 256 thr (4 waves = kq x nh)
__global__ __launch_bounds__(256, 3) void k_corr(const __hip_bfloat16* __restrict__ pad,
                                                 float* __restrict__ out){
  __shared__ alignas(16) short s_a[38*512];   // A tile: 38 rows x 1KB frag-blocks
  int bid = blockIdx.x;
  int b = bid & 7;
  int r0 = bid >> 3;
  int mh = r0 & 1;
  int combo = r0 >> 1;
  int dx, d0;
  if (combo == 0){ dx = 0; d0 = 0; }
  else if (combo == 1){ dx = 0; d0 = 4; }
  else { int q = combo - 2; dx = 1 + q/3; d0 = -10 + 7*(q - 3*(q/3)); }

  int tid = threadIdx.x;
  int lane = tid & 63, wvi = tid >> 6;
  int kq = wvi >> 1, nh = wvi & 1;

  int rA = dx & 1;
  const __hip_bfloat16* padA = pad + (size_t)((rA*8 + b)*32 + mh*16)*CH_ELEMS;
  const __hip_bfloat16* padB = pad + (size_t)((16  + b)*32 + nh*16)*CH_ELEMS; // copy 2

  floatx4 acc[7];
  #pragma unroll
  for (int d = 0; d < 7; ++d) acc[d] = (floatx4)(0.f);

  // staging roles
  int sch = tid >> 4, sxd = tid & 15;
  const unsigned int* gAc = (const unsigned int*)(padA + (size_t)sch*CH_ELEMS);
  unsigned int lidx = (unsigned int)((sch + ((sxd >> 2) << 4))*4 + (sxd & 3));
  unsigned int* sw = (unsigned int*)s_a;
  const short8* sr = (const short8*)s_a;
  const short8* gB = (const short8*)(padB + (size_t)(lane & 15)*CH_ELEMS);

  for (int xi = 0; xi < 4; ++xi){
    int x0 = xi << 5;
    int xx0A = x0 + dx + 10 + rA;                 // even -> dword aligned
    int xxB  = x0 + 16 + ((lane >> 4) << 3);      // mult of 8 -> 16B aligned
    for (int yi = 0; yi < 4; ++yi){
      int Y0 = yi << 5;
      // ---- stage A tile: rows [Y0+d0, Y0+d0+37] ----
      {
        int yy0 = Y0 + d0 + 10;
        const unsigned int* g = gAc + ((yy0*XP + xx0A) >> 1) + sxd;
        #pragma unroll 8
        for (int s = 0; s < 38; ++s)
          sw[(unsigned)(s*256) + lidx] = g[s*80];
      }
      __syncthreads();
      // ---- compute ----
      {
        int ybase = Y0 + (kq << 4);
        int sbase = kq << 4;
        short8 ring[8];
        #pragma unroll
        for (int w = 0; w < 7; ++w) ring[w] = sr[(sbase + w)*64 + lane];
        const short8* gBp = gB + (((ybase + 10)*XP + xxB) >> 3);
        short8 BQ[8];
        #pragma unroll
        for (int k = 0; k < 8; ++k) BQ[k] = gBp[k*20];   // XP/8 = 20 per row
        #pragma unroll
        for (int yl = 0; yl < 16; ++yl){
          short8 bf = BQ[yl & 7];
          #pragma unroll
          for (int d = 0; d < 7; ++d)
            acc[d] = __builtin_amdgcn_mfma_f32_16x16x32_bf16(ring[(yl + d) & 7], bf, acc[d], 0, 0, 0);
          if (yl < 15) ring[(yl + 7) & 7] = sr[(sbase + yl + 7)*64 + lane];
          if (yl < 8)  BQ[yl & 7] = gBp[(yl + 8)*20];
        }
      }
      __syncthreads();
    }
  }

  // ---- kq reduction via LDS (deterministic, no atomics) ----
  float* sf = (float*)s_a;
  if (kq == 1){
    #pragma unroll
    for (int d = 0; d < 7; ++d)
      #pragma unroll
      for (int q = 0; q < 4; ++q)
        sf[(((nh*7 + d)*4 + q) << 6) + lane] = acc[d][q];
  }
  __syncthreads();
  if (kq == 0){
    int base_b = b * 528 * 441;
    #pragma unroll
    for (int d = 0; d < 7; ++d){
      int dy = d0 + d;
      #pragma unroll
      for (int q = 0; q < 4; ++q){
        float v = acc[d][q] + sf[(((nh*7 + d)*4 + q) << 6) + lane];
        int m = ((lane >> 4) << 2) + q;          // C row (M = i)
        int n = lane & 15;                        // C col (N = j)
        int i = (mh << 4) + m;
        int j = (nh << 4) + n;
        if (i <= j){
          int p = i*(65 - i)/2 + (j - i);
          out[base_b + p*441 + (10 + dy)*21 + (10 + dx)] = v;
          if (i == j && (dy != 0 || dx != 0))
            out[base_b + p*441 + (10 - dy)*21 + (10 - dx)] = v;   // autocorr symmetry
        } else {
          int p = j*(65 - j)/2 + (i - j);
          out[base_b + p*441 + (10 - dy)*21 + (10 - dx)] = v;     // pair (j,i) at (-dy,-dx)
        }
      }
    }
  }
}

extern "C" void kernel_launch(void* const* d_in, const int* in_sizes, int n_in,
                              void* d_out, int out_size, void* d_ws, size_t ws_size,
                              hipStream_t stream){
  const float* x = (const float*)d_in[0];
  __hip_bfloat16* pad = (__hip_bfloat16*)d_ws;   // 3*256*23680*2 = ~36.4 MB
  float* out = (float*)d_out;
  k_std<<<dim3(256), dim3(256), 0, stream>>>(x, pad);
  k_corr<<<dim3(512), dim3(256), 0, stream>>>(pad, out);
}